// Round 16
// baseline (212.240 us; speedup 1.0000x reference)
//
#include <hip/hip_runtime.h>
#include <math.h>

#define HH 64
#define WW 64
#define CC 256
#define NHEAD 8
#define HD 32
#define KW 7

#define KR 40    // natten K LDS row stride (u16)
#define VTS 232  // natten Vt row stride (u16)
#define NBLK 768u

typedef _Float16 half8v __attribute__((ext_vector_type(8)));
typedef __fp16 fp16x2 __attribute__((ext_vector_type(2)));
typedef float float4v __attribute__((ext_vector_type(4)));

__device__ unsigned g_bar1, g_bar2, g_ack;  // zero-init at module load

__device__ __forceinline__ unsigned pkrtz(float lo, float hi) {
  union { fp16x2 h; unsigned u; } c;
  c.h = __builtin_amdgcn_cvt_pkrtz(lo, hi);
  return c.u;
}
__device__ __forceinline__ ushort f2h(float f) {
  union { _Float16 h; ushort u; } c;
  c.h = (_Float16)f;
  return c.u;
}

// device-scope grid barrier: all NBLK blocks co-resident by construction
// (grid 768 <= 256 CU x 3 blocks/CU guaranteed by launch_bounds(256,3)).
__device__ __forceinline__ void grid_barrier(unsigned* cnt, int t) {
  __syncthreads();
  if (t == 0) {
    __hip_atomic_fetch_add(cnt, 1u, __ATOMIC_ACQ_REL, __HIP_MEMORY_SCOPE_AGENT);
    while (__hip_atomic_load(cnt, __ATOMIC_ACQUIRE, __HIP_MEMORY_SCOPE_AGENT) <
           NBLK)
      __builtin_amdgcn_s_sleep(2);
  }
  __syncthreads();
}

// ---- gemm tile device function (R12's gemm5h body, proven) ------------------
template <int N, int BM, int BN, bool ABF, bool OB>
__device__ __forceinline__ void gemm_tile(
    char* smem, const void* __restrict__ Ap, const float* __restrict__ Bw,
    const float* __restrict__ bias, void* __restrict__ Cd,
    int bm, int bn, int t) {
  constexpr int SEGA = BM / 32;
  constexpr int SEGB = BN / 32;
  constexpr int MF = BM / 32;
  constexpr int NF = BN / 32;
  constexpr int ABUF = BM * 128;
  constexpr int BBUF = BN * 128;

  ushort* As0 = (ushort*)smem;
  ushort* Bs0 = (ushort*)(smem + 2 * ABUF);

  const int lane = t & 63;
  const int wave = t >> 6;

  const float*  Aw = (const float*)Ap;
  const ushort* Ab = (const ushort*)Ap;

  float fA[2][SEGA][8];
  float fB[2][SEGB][8];
  uint4 wA[2][SEGA];

#define LOADA(c, s)                                                            \
  {                                                                            \
    _Pragma("unroll") for (int sa = 0; sa < SEGA; ++sa) {                      \
      const int seg = sa * 256 + t;                                            \
      const int row = seg >> 3;                                                \
      const int q8 = seg & 7;                                                  \
      if (ABF) {                                                               \
        wA[s][sa] =                                                            \
            *(const uint4*)(Ab + (size_t)(bm + row) * 256 + (c) * 64 + q8 * 8);\
      } else {                                                                 \
        const float* p_ = Aw + (size_t)(bm + row) * 256 + (c) * 64 + q8 * 8;   \
        *(float4*)&fA[s][sa][0] = *(const float4*)(p_);                        \
        *(float4*)&fA[s][sa][4] = *(const float4*)(p_ + 4);                    \
      }                                                                        \
    }                                                                          \
  }

#define LOADB(c, s)                                                            \
  {                                                                            \
    _Pragma("unroll") for (int sb = 0; sb < SEGB; ++sb) {                      \
      const int seg = sb * 256 + t;                                            \
      const int row = seg >> 3;                                                \
      const int q8 = seg & 7;                                                  \
      const float* p_ = Bw + (size_t)(bn + row) * 256 + (c) * 64 + q8 * 8;     \
      *(float4*)&fB[s][sb][0] = *(const float4*)(p_);                          \
      *(float4*)&fB[s][sb][4] = *(const float4*)(p_ + 4);                      \
    }                                                                          \
  }

#define WRITEC(b, s)                                                           \
  {                                                                            \
    _Pragma("unroll") for (int sa = 0; sa < SEGA; ++sa) {                      \
      const int seg = sa * 256 + t;                                            \
      const int row = seg >> 3;                                                \
      const int q8 = seg & 7;                                                  \
      const int lin = row * 128 + q8 * 16;                                     \
      const int sw = (row & 7) << 4;                                           \
      uint4 w_;                                                                \
      if (ABF) {                                                               \
        w_ = wA[s][sa];                                                        \
      } else {                                                                 \
        w_.x = pkrtz(fA[s][sa][0], fA[s][sa][1]);                              \
        w_.y = pkrtz(fA[s][sa][2], fA[s][sa][3]);                              \
        w_.z = pkrtz(fA[s][sa][4], fA[s][sa][5]);                              \
        w_.w = pkrtz(fA[s][sa][6], fA[s][sa][7]);                              \
      }                                                                        \
      *(uint4*)((char*)As0 + (b) * ABUF + (lin ^ sw)) = w_;                    \
    }                                                                          \
    _Pragma("unroll") for (int sb = 0; sb < SEGB; ++sb) {                      \
      const int seg = sb * 256 + t;                                            \
      const int row = seg >> 3;                                                \
      const int q8 = seg & 7;                                                  \
      const int lin = row * 128 + q8 * 16;                                     \
      const int sw = (row & 7) << 4;                                           \
      uint4 w_;                                                                \
      w_.x = pkrtz(fB[s][sb][0], fB[s][sb][1]);                                \
      w_.y = pkrtz(fB[s][sb][2], fB[s][sb][3]);                                \
      w_.z = pkrtz(fB[s][sb][4], fB[s][sb][5]);                                \
      w_.w = pkrtz(fB[s][sb][6], fB[s][sb][7]);                                \
      *(uint4*)((char*)Bs0 + (b) * BBUF + (lin ^ sw)) = w_;                    \
    }                                                                          \
  }

  const int wr = (wave >> 1) * (BM / 2);
  const int wc = (wave & 1) * (BN / 2);
  const int lrow = lane & 15;
  const int lkb = (lane >> 4) * 16;

  float4v acc[MF][NF];
#pragma unroll
  for (int mf = 0; mf < MF; ++mf)
#pragma unroll
    for (int nf = 0; nf < NF; ++nf) acc[mf][nf] = (float4v){0.f, 0.f, 0.f, 0.f};

  LOADA(0, 0); LOADB(0, 0);
  WRITEC(0, 0);
  LOADA(1, 1); LOADB(1, 1);
  __syncthreads();

#pragma unroll
  for (int c = 0; c < 4; ++c) {
    if (c < 3) WRITEC((c + 1) & 1, (c + 1) & 1);
    if (c < 2) { LOADA(c + 2, c & 1); LOADB(c + 2, c & 1); }
    const char* Al = (const char*)As0 + (c & 1) * ABUF;
    const char* Bl = (const char*)Bs0 + (c & 1) * BBUF;
#pragma unroll
    for (int ks = 0; ks < 2; ++ks) {
      half8v af[MF], bfr[NF];
#pragma unroll
      for (int mf = 0; mf < MF; ++mf) {
        const int row = wr + mf * 16 + lrow;
        const int ad = row * 128 + ks * 64 + lkb;
        af[mf] = *(const half8v*)(Al + (ad ^ ((row & 7) << 4)));
      }
#pragma unroll
      for (int nf = 0; nf < NF; ++nf) {
        const int row = wc + nf * 16 + lrow;
        const int bd = row * 128 + ks * 64 + lkb;
        bfr[nf] = *(const half8v*)(Bl + (bd ^ ((row & 7) << 4)));
      }
#pragma unroll
      for (int mf = 0; mf < MF; ++mf)
#pragma unroll
        for (int nf = 0; nf < NF; ++nf)
          acc[mf][nf] = __builtin_amdgcn_mfma_f32_16x16x32_f16(
              af[mf], bfr[nf], acc[mf][nf], 0, 0, 0);
    }
    if (c < 3) __syncthreads();
  }
#undef LOADA
#undef LOADB
#undef WRITEC

#pragma unroll
  for (int mf = 0; mf < MF; ++mf) {
#pragma unroll
    for (int nf = 0; nf < NF; ++nf) {
      const int n = bn + wc + nf * 16 + lrow;
      const float bv = bias[n];
      const int m0 = bm + wr + mf * 16 + (lane >> 4) * 4;
      if (OB) {
        ushort* C = (ushort*)Cd;
#pragma unroll
        for (int rr = 0; rr < 4; ++rr)
          C[(size_t)(m0 + rr) * N + n] = f2h(acc[mf][nf][rr] + bv);
      } else {
        float* C = (float*)Cd;
#pragma unroll
        for (int rr = 0; rr < 4; ++rr)
          C[(size_t)(m0 + rr) * N + n] = acc[mf][nf][rr] + bv;
      }
    }
  }
}

// ---- natten unit device function (R13's natten7 body, proven) ---------------
__device__ __forceinline__ void natten_unit(
    char* smem, const ushort* __restrict__ qkv, const float* __restrict__ rpb,
    ushort* __restrict__ aout, int tile, int head, int t) {
  ushort* Ks = (ushort*)smem;
  ushort* Vt = (ushort*)(smem + 17920);
  float*  Rs = (float*)(smem + 32768);

  const int i0 = (tile >> 3) * 8, j0 = (tile & 7) * 8;
  const int hs = min(max(i0 - 3, 0), HH - 14);
  const int ws = min(max(j0 - 3, 0), WW - 14);
  const int l = t & 63;
  const int wv = t >> 6;

  if (t < 169) Rs[t] = rpb[head * 169 + t];

  if (t < 112) {
    const int ent2 = t >> 2;
    const int hr = ent2 >> 1, hc = 14 + (ent2 & 1);
    const uint4 z = {0u, 0u, 0u, 0u};
    *(uint4*)(Ks + (hr * 16 + hc) * KR + (t & 3) * 8) = z;
  }
#pragma unroll
  for (int it = 0; it < 2; ++it) {
    const int task = it * 256 + t;
    const int d = task >> 4, hr = task & 15;
    if (hr < 14) *(unsigned*)(Vt + d * VTS + hr * 16 + 14) = 0u;
  }

#pragma unroll
  for (int s = 0; s < 4; ++s) {
    if (t < 196) {
      const int hr = (t * 2341) >> 15;
      const int hc = t - hr * 14;
      const int g = (hs + hr) * WW + (ws + hc);
      const int col = hr * 16 + hc;
      const uint4 kv = *(const uint4*)(qkv + (size_t)g * 768 + 256 + head * HD + s * 8);
      *(uint4*)(Ks + col * KR + s * 8) = kv;
      const uint4 vv = *(const uint4*)(qkv + (size_t)g * 768 + 512 + head * HD + s * 8);
      const int d0 = s * 8;
      Vt[(d0 + 0) * VTS + col] = (ushort)(vv.x);
      Vt[(d0 + 1) * VTS + col] = (ushort)(vv.x >> 16);
      Vt[(d0 + 2) * VTS + col] = (ushort)(vv.y);
      Vt[(d0 + 3) * VTS + col] = (ushort)(vv.y >> 16);
      Vt[(d0 + 4) * VTS + col] = (ushort)(vv.z);
      Vt[(d0 + 5) * VTS + col] = (ushort)(vv.z >> 16);
      Vt[(d0 + 6) * VTS + col] = (ushort)(vv.w);
      Vt[(d0 + 7) * VTS + col] = (ushort)(vv.w >> 16);
    }
  }
  __syncthreads();

  const int strip_i0 = i0 + wv * 2;
  const int lg = l >> 4;
  const int l15 = l & 15;

  const int pi = strip_i0 + (l15 >> 3);
  const int pj = j0 + (l15 & 7);
  const int si = min(max(pi - 3, 0), HH - KW);
  const int sj = min(max(pj - 3, 0), WW - KW);
  const int si_min = min(max(strip_i0 - 3, 0), HH - KW);
  const int slab0 = min(si_min - hs, 6);

  const half8v qf = *(const half8v*)(qkv + (size_t)(pi * WW + pj) * 768 +
                                     head * HD + lg * 8);

  float4v s8[8];
  const float4v zz = {0.f, 0.f, 0.f, 0.f};
#pragma unroll
  for (int g = 0; g < 8; ++g) {
    const int ent = (slab0 + g) * 16 + l15;
    const half8v kf = *(const half8v*)(Ks + ent * KR + lg * 8);
    s8[g] = __builtin_amdgcn_mfma_f32_16x16x32_f16(kf, qf, zz, 0, 0, 0);
  }

  const int lr0 = si - hs;
  const int lc0 = sj - ws;
  const int abase = slab0 - lr0;
  const int rowb = ((si - pi + 6) + abase) * 13 + (sj - pj + 6) - lc0;
  const float scale = 0.17677669529663687f;

  float e8[8][4];
  float ssum = 0.f;
#pragma unroll
  for (int g = 0; g < 8; ++g) {
    const int a = abase + g;
    const bool va = (unsigned)a < 7u;
    const int idxg = min(max(rowb + g * 13, 0), 153);
#pragma unroll
    for (int r = 0; r < 4; ++r) {
      const int hc = lg * 4 + r;
      const bool vc = (unsigned)(hc - lc0) < 7u;
      const float ev = __expf(fmaf(s8[g][r], scale, Rs[idxg + hc]));
      const float em = (va && vc) ? ev : 0.f;
      e8[g][r] = em;
      ssum += em;
    }
  }
  ssum += __shfl_xor(ssum, 16);
  ssum += __shfl_xor(ssum, 32);
  const float inv = 1.f / ssum;

  unsigned Wp[8][2];
#pragma unroll
  for (int g = 0; g < 8; ++g) {
    Wp[g][0] = pkrtz(e8[g][0] * inv, e8[g][1] * inv);
    Wp[g][1] = pkrtz(e8[g][2] * inv, e8[g][3] * inv);
  }

  float4v o[2] = {zz, zz};
#pragma unroll
  for (int ks = 0; ks < 4; ++ks) {
    unsigned F[4];
#pragma unroll
    for (int f = 0; f < 4; ++f) {
      const int src = l15 + (((lg & 1) * 2 + (f >> 1)) << 4);
      const unsigned va = __shfl(Wp[2 * ks][f & 1], src);
      const unsigned vb = __shfl(Wp[2 * ks + 1][f & 1], src);
      F[f] = (lg >> 1) ? vb : va;
    }
    union { unsigned u[4]; half8v h; } pf;
    pf.u[0] = F[0]; pf.u[1] = F[1]; pf.u[2] = F[2]; pf.u[3] = F[3];
#pragma unroll
    for (int nf = 0; nf < 2; ++nf) {
      const int dim = l15 + nf * 16;
      const half8v vf = *(const half8v*)(Vt + dim * VTS + slab0 * 16 +
                                         ks * 32 + lg * 8);
      o[nf] = __builtin_amdgcn_mfma_f32_16x16x32_f16(pf.h, vf, o[nf], 0, 0, 0);
    }
  }

#pragma unroll
  for (int r = 0; r < 4; ++r) {
    const int pxo = lg * 4 + r;
    const int oi = strip_i0 + (pxo >> 3);
    const int oj = j0 + (pxo & 7);
    ushort* op = aout + (size_t)(oi * WW + oj) * CC + head * HD + l15;
    op[0]  = f2h(o[0][r]);
    op[16] = f2h(o[1][r]);
  }
}

// ---- fused: gemm1 | atomic grid barrier | natten | barrier | gemm2 ----------
__global__ __launch_bounds__(256, 3) void meganat(
    const float* x, const float* qkv_w, const float* qkv_b,
    const float* proj_w, const float* proj_b, const float* rpb,
    float* out, ushort* qkvh, ushort* aouth) {
  __shared__ __align__(16) char smem[33472];
  const int blk = blockIdx.x;
  const int t = threadIdx.x;

  // phase 1: QKV projection, 1536 tiles of 32x64, 2 per block
  gemm_tile<768, 32, 64, false, true>(smem, x, qkv_w, qkv_b, qkvh,
                                      (blk & 127) * 32, (blk >> 7) * 64, t);
  __syncthreads();
  {
    const int t1 = blk + 768;
    gemm_tile<768, 32, 64, false, true>(smem, x, qkv_w, qkv_b, qkvh,
                                        (t1 & 127) * 32, (t1 >> 7) * 64, t);
  }
  grid_barrier(&g_bar1, t);

  // phase 2: neighborhood attention, 512 units (64 tiles x 8 heads)
  if (blk < 512) natten_unit(smem, qkvh, rpb, aouth, blk & 63, blk >> 6, t);
  grid_barrier(&g_bar2, t);

  // counter reset for next launch (graph replay): ack + block0 resets
  if (t == 0) {
    __hip_atomic_fetch_add(&g_ack, 1u, __ATOMIC_ACQ_REL,
                           __HIP_MEMORY_SCOPE_AGENT);
    if (blk == 0) {
      while (__hip_atomic_load(&g_ack, __ATOMIC_ACQUIRE,
                               __HIP_MEMORY_SCOPE_AGENT) < NBLK)
        __builtin_amdgcn_s_sleep(2);
      __hip_atomic_store(&g_bar1, 0u, __ATOMIC_RELAXED,
                         __HIP_MEMORY_SCOPE_AGENT);
      __hip_atomic_store(&g_bar2, 0u, __ATOMIC_RELAXED,
                         __HIP_MEMORY_SCOPE_AGENT);
      __hip_atomic_store(&g_ack, 0u, __ATOMIC_RELEASE,
                         __HIP_MEMORY_SCOPE_AGENT);
    }
  }

  // phase 3: output projection, 1024 tiles of 32x32
  gemm_tile<256, 32, 32, true, false>(smem, aouth, proj_w, proj_b, out,
                                      (blk & 127) * 32, (blk >> 7) * 32, t);
  if (blk < 256) {
    __syncthreads();
    const int t1 = blk + 768;
    gemm_tile<256, 32, 32, true, false>(smem, aouth, proj_w, proj_b, out,
                                        (t1 & 127) * 32, (t1 >> 7) * 32, t);
  }
}

extern "C" void kernel_launch(void* const* d_in, const int* in_sizes, int n_in,
                              void* d_out, int out_size, void* d_ws, size_t ws_size,
                              hipStream_t stream) {
  const float* x      = (const float*)d_in[0];
  const float* qkv_w  = (const float*)d_in[1];
  const float* qkv_b  = (const float*)d_in[2];
  const float* proj_w = (const float*)d_in[3];
  const float* proj_b = (const float*)d_in[4];
  const float* rpb    = (const float*)d_in[5];
  float* out = (float*)d_out;

  ushort* qkvh  = (ushort*)d_ws;            // [4096,768] f16
  ushort* aouth = qkvh + 3145728;           // [4096,256] f16

  meganat<<<dim3(NBLK), dim3(256), 0, stream>>>(
      x, qkv_w, qkv_b, proj_w, proj_b, rpb, out, qkvh, aouth);
}

// Round 17
// 206.844 us; speedup vs baseline: 1.0261x; 1.0261x over previous
//
#include <hip/hip_runtime.h>
#include <math.h>

#define HH 64
#define WW 64
#define CC 256
#define NHEAD 8
#define HD 32
#define KW 7

#define KR 40    // natten K LDS row stride (u16)
#define VTS 232  // natten Vt row stride (u16)
#define NBLK 768u

typedef _Float16 half8v __attribute__((ext_vector_type(8)));
typedef __fp16 fp16x2 __attribute__((ext_vector_type(2)));
typedef float float4v __attribute__((ext_vector_type(4)));

__device__ unsigned g_bar1, g_bar2, g_ack;  // zero-init at module load

__device__ __forceinline__ unsigned pkrtz(float lo, float hi) {
  union { fp16x2 h; unsigned u; } c;
  c.h = __builtin_amdgcn_cvt_pkrtz(lo, hi);
  return c.u;
}
__device__ __forceinline__ ushort f2h(float f) {
  union { _Float16 h; ushort u; } c;
  c.h = (_Float16)f;
  return c.u;
}

// Device-scope grid barrier. All NBLK blocks co-resident (LDS 33.8KB -> 4
// blocks/CU >= 768/256; verified live in R16). Key perf fix vs R16: poll
// with RELAXED loads (no per-poll cache ops); exactly ONE release fence
// before the increment and ONE acquire fence after the poll.
__device__ __forceinline__ void grid_barrier(unsigned* cnt, int t) {
  __syncthreads();
  if (t == 0) {
    __threadfence();  // release: write back this block's L2 (qkvh/aouth)
    __hip_atomic_fetch_add(cnt, 1u, __ATOMIC_RELAXED,
                           __HIP_MEMORY_SCOPE_AGENT);
    while (__hip_atomic_load(cnt, __ATOMIC_RELAXED,
                             __HIP_MEMORY_SCOPE_AGENT) < NBLK)
      __builtin_amdgcn_s_sleep(8);
    __threadfence();  // acquire: invalidate stale lines before consuming
  }
  __syncthreads();
}

// ---- gemm tile device function (R12's gemm5h body, proven) ------------------
template <int N, int BM, int BN, bool ABF, bool OB>
__device__ __forceinline__ void gemm_tile(
    char* smem, const void* __restrict__ Ap, const float* __restrict__ Bw,
    const float* __restrict__ bias, void* __restrict__ Cd,
    int bm, int bn, int t) {
  constexpr int SEGA = BM / 32;
  constexpr int SEGB = BN / 32;
  constexpr int MF = BM / 32;
  constexpr int NF = BN / 32;
  constexpr int ABUF = BM * 128;
  constexpr int BBUF = BN * 128;

  ushort* As0 = (ushort*)smem;
  ushort* Bs0 = (ushort*)(smem + 2 * ABUF);

  const int lane = t & 63;
  const int wave = t >> 6;

  const float*  Aw = (const float*)Ap;
  const ushort* Ab = (const ushort*)Ap;

  float fA[2][SEGA][8];
  float fB[2][SEGB][8];
  uint4 wA[2][SEGA];

#define LOADA(c, s)                                                            \
  {                                                                            \
    _Pragma("unroll") for (int sa = 0; sa < SEGA; ++sa) {                      \
      const int seg = sa * 256 + t;                                            \
      const int row = seg >> 3;                                                \
      const int q8 = seg & 7;                                                  \
      if (ABF) {                                                               \
        wA[s][sa] =                                                            \
            *(const uint4*)(Ab + (size_t)(bm + row) * 256 + (c) * 64 + q8 * 8);\
      } else {                                                                 \
        const float* p_ = Aw + (size_t)(bm + row) * 256 + (c) * 64 + q8 * 8;   \
        *(float4*)&fA[s][sa][0] = *(const float4*)(p_);                        \
        *(float4*)&fA[s][sa][4] = *(const float4*)(p_ + 4);                    \
      }                                                                        \
    }                                                                          \
  }

#define LOADB(c, s)                                                            \
  {                                                                            \
    _Pragma("unroll") for (int sb = 0; sb < SEGB; ++sb) {                      \
      const int seg = sb * 256 + t;                                            \
      const int row = seg >> 3;                                                \
      const int q8 = seg & 7;                                                  \
      const float* p_ = Bw + (size_t)(bn + row) * 256 + (c) * 64 + q8 * 8;     \
      *(float4*)&fB[s][sb][0] = *(const float4*)(p_);                          \
      *(float4*)&fB[s][sb][4] = *(const float4*)(p_ + 4);                      \
    }                                                                          \
  }

#define WRITEC(b, s)                                                           \
  {                                                                            \
    _Pragma("unroll") for (int sa = 0; sa < SEGA; ++sa) {                      \
      const int seg = sa * 256 + t;                                            \
      const int row = seg >> 3;                                                \
      const int q8 = seg & 7;                                                  \
      const int lin = row * 128 + q8 * 16;                                     \
      const int sw = (row & 7) << 4;                                           \
      uint4 w_;                                                                \
      if (ABF) {                                                               \
        w_ = wA[s][sa];                                                        \
      } else {                                                                 \
        w_.x = pkrtz(fA[s][sa][0], fA[s][sa][1]);                              \
        w_.y = pkrtz(fA[s][sa][2], fA[s][sa][3]);                              \
        w_.z = pkrtz(fA[s][sa][4], fA[s][sa][5]);                              \
        w_.w = pkrtz(fA[s][sa][6], fA[s][sa][7]);                              \
      }                                                                        \
      *(uint4*)((char*)As0 + (b) * ABUF + (lin ^ sw)) = w_;                    \
    }                                                                          \
    _Pragma("unroll") for (int sb = 0; sb < SEGB; ++sb) {                      \
      const int seg = sb * 256 + t;                                            \
      const int row = seg >> 3;                                                \
      const int q8 = seg & 7;                                                  \
      const int lin = row * 128 + q8 * 16;                                     \
      const int sw = (row & 7) << 4;                                           \
      uint4 w_;                                                                \
      w_.x = pkrtz(fB[s][sb][0], fB[s][sb][1]);                                \
      w_.y = pkrtz(fB[s][sb][2], fB[s][sb][3]);                                \
      w_.z = pkrtz(fB[s][sb][4], fB[s][sb][5]);                                \
      w_.w = pkrtz(fB[s][sb][6], fB[s][sb][7]);                                \
      *(uint4*)((char*)Bs0 + (b) * BBUF + (lin ^ sw)) = w_;                    \
    }                                                                          \
  }

  const int wr = (wave >> 1) * (BM / 2);
  const int wc = (wave & 1) * (BN / 2);
  const int lrow = lane & 15;
  const int lkb = (lane >> 4) * 16;

  float4v acc[MF][NF];
#pragma unroll
  for (int mf = 0; mf < MF; ++mf)
#pragma unroll
    for (int nf = 0; nf < NF; ++nf) acc[mf][nf] = (float4v){0.f, 0.f, 0.f, 0.f};

  LOADA(0, 0); LOADB(0, 0);
  WRITEC(0, 0);
  LOADA(1, 1); LOADB(1, 1);
  __syncthreads();

#pragma unroll
  for (int c = 0; c < 4; ++c) {
    if (c < 3) WRITEC((c + 1) & 1, (c + 1) & 1);
    if (c < 2) { LOADA(c + 2, c & 1); LOADB(c + 2, c & 1); }
    const char* Al = (const char*)As0 + (c & 1) * ABUF;
    const char* Bl = (const char*)Bs0 + (c & 1) * BBUF;
#pragma unroll
    for (int ks = 0; ks < 2; ++ks) {
      half8v af[MF], bfr[NF];
#pragma unroll
      for (int mf = 0; mf < MF; ++mf) {
        const int row = wr + mf * 16 + lrow;
        const int ad = row * 128 + ks * 64 + lkb;
        af[mf] = *(const half8v*)(Al + (ad ^ ((row & 7) << 4)));
      }
#pragma unroll
      for (int nf = 0; nf < NF; ++nf) {
        const int row = wc + nf * 16 + lrow;
        const int bd = row * 128 + ks * 64 + lkb;
        bfr[nf] = *(const half8v*)(Bl + (bd ^ ((row & 7) << 4)));
      }
#pragma unroll
      for (int mf = 0; mf < MF; ++mf)
#pragma unroll
        for (int nf = 0; nf < NF; ++nf)
          acc[mf][nf] = __builtin_amdgcn_mfma_f32_16x16x32_f16(
              af[mf], bfr[nf], acc[mf][nf], 0, 0, 0);
    }
    if (c < 3) __syncthreads();
  }
#undef LOADA
#undef LOADB
#undef WRITEC

#pragma unroll
  for (int mf = 0; mf < MF; ++mf) {
#pragma unroll
    for (int nf = 0; nf < NF; ++nf) {
      const int n = bn + wc + nf * 16 + lrow;
      const float bv = bias[n];
      const int m0 = bm + wr + mf * 16 + (lane >> 4) * 4;
      if (OB) {
        ushort* C = (ushort*)Cd;
#pragma unroll
        for (int rr = 0; rr < 4; ++rr)
          C[(size_t)(m0 + rr) * N + n] = f2h(acc[mf][nf][rr] + bv);
      } else {
        float* C = (float*)Cd;
#pragma unroll
        for (int rr = 0; rr < 4; ++rr)
          C[(size_t)(m0 + rr) * N + n] = acc[mf][nf][rr] + bv;
      }
    }
  }
}

// ---- natten unit device function (R13's natten7 body, proven) ---------------
__device__ __forceinline__ void natten_unit(
    char* smem, const ushort* __restrict__ qkv, const float* __restrict__ rpb,
    ushort* __restrict__ aout, int tile, int head, int t) {
  ushort* Ks = (ushort*)smem;
  ushort* Vt = (ushort*)(smem + 17920);
  float*  Rs = (float*)(smem + 32768);

  const int i0 = (tile >> 3) * 8, j0 = (tile & 7) * 8;
  const int hs = min(max(i0 - 3, 0), HH - 14);
  const int ws = min(max(j0 - 3, 0), WW - 14);
  const int l = t & 63;
  const int wv = t >> 6;

  if (t < 169) Rs[t] = rpb[head * 169 + t];

  if (t < 112) {
    const int ent2 = t >> 2;
    const int hr = ent2 >> 1, hc = 14 + (ent2 & 1);
    const uint4 z = {0u, 0u, 0u, 0u};
    *(uint4*)(Ks + (hr * 16 + hc) * KR + (t & 3) * 8) = z;
  }
#pragma unroll
  for (int it = 0; it < 2; ++it) {
    const int task = it * 256 + t;
    const int d = task >> 4, hr = task & 15;
    if (hr < 14) *(unsigned*)(Vt + d * VTS + hr * 16 + 14) = 0u;
  }

#pragma unroll
  for (int s = 0; s < 4; ++s) {
    if (t < 196) {
      const int hr = (t * 2341) >> 15;
      const int hc = t - hr * 14;
      const int g = (hs + hr) * WW + (ws + hc);
      const int col = hr * 16 + hc;
      const uint4 kv = *(const uint4*)(qkv + (size_t)g * 768 + 256 + head * HD + s * 8);
      *(uint4*)(Ks + col * KR + s * 8) = kv;
      const uint4 vv = *(const uint4*)(qkv + (size_t)g * 768 + 512 + head * HD + s * 8);
      const int d0 = s * 8;
      Vt[(d0 + 0) * VTS + col] = (ushort)(vv.x);
      Vt[(d0 + 1) * VTS + col] = (ushort)(vv.x >> 16);
      Vt[(d0 + 2) * VTS + col] = (ushort)(vv.y);
      Vt[(d0 + 3) * VTS + col] = (ushort)(vv.y >> 16);
      Vt[(d0 + 4) * VTS + col] = (ushort)(vv.z);
      Vt[(d0 + 5) * VTS + col] = (ushort)(vv.z >> 16);
      Vt[(d0 + 6) * VTS + col] = (ushort)(vv.w);
      Vt[(d0 + 7) * VTS + col] = (ushort)(vv.w >> 16);
    }
  }
  __syncthreads();

  const int strip_i0 = i0 + wv * 2;
  const int lg = l >> 4;
  const int l15 = l & 15;

  const int pi = strip_i0 + (l15 >> 3);
  const int pj = j0 + (l15 & 7);
  const int si = min(max(pi - 3, 0), HH - KW);
  const int sj = min(max(pj - 3, 0), WW - KW);
  const int si_min = min(max(strip_i0 - 3, 0), HH - KW);
  const int slab0 = min(si_min - hs, 6);

  const half8v qf = *(const half8v*)(qkv + (size_t)(pi * WW + pj) * 768 +
                                     head * HD + lg * 8);

  float4v s8[8];
  const float4v zz = {0.f, 0.f, 0.f, 0.f};
#pragma unroll
  for (int g = 0; g < 8; ++g) {
    const int ent = (slab0 + g) * 16 + l15;
    const half8v kf = *(const half8v*)(Ks + ent * KR + lg * 8);
    s8[g] = __builtin_amdgcn_mfma_f32_16x16x32_f16(kf, qf, zz, 0, 0, 0);
  }

  const int lr0 = si - hs;
  const int lc0 = sj - ws;
  const int abase = slab0 - lr0;
  const int rowb = ((si - pi + 6) + abase) * 13 + (sj - pj + 6) - lc0;
  const float scale = 0.17677669529663687f;

  float e8[8][4];
  float ssum = 0.f;
#pragma unroll
  for (int g = 0; g < 8; ++g) {
    const int a = abase + g;
    const bool va = (unsigned)a < 7u;
    const int idxg = min(max(rowb + g * 13, 0), 153);
#pragma unroll
    for (int r = 0; r < 4; ++r) {
      const int hc = lg * 4 + r;
      const bool vc = (unsigned)(hc - lc0) < 7u;
      const float ev = __expf(fmaf(s8[g][r], scale, Rs[idxg + hc]));
      const float em = (va && vc) ? ev : 0.f;
      e8[g][r] = em;
      ssum += em;
    }
  }
  ssum += __shfl_xor(ssum, 16);
  ssum += __shfl_xor(ssum, 32);
  const float inv = 1.f / ssum;

  unsigned Wp[8][2];
#pragma unroll
  for (int g = 0; g < 8; ++g) {
    Wp[g][0] = pkrtz(e8[g][0] * inv, e8[g][1] * inv);
    Wp[g][1] = pkrtz(e8[g][2] * inv, e8[g][3] * inv);
  }

  float4v o[2] = {zz, zz};
#pragma unroll
  for (int ks = 0; ks < 4; ++ks) {
    unsigned F[4];
#pragma unroll
    for (int f = 0; f < 4; ++f) {
      const int src = l15 + (((lg & 1) * 2 + (f >> 1)) << 4);
      const unsigned va = __shfl(Wp[2 * ks][f & 1], src);
      const unsigned vb = __shfl(Wp[2 * ks + 1][f & 1], src);
      F[f] = (lg >> 1) ? vb : va;
    }
    union { unsigned u[4]; half8v h; } pf;
    pf.u[0] = F[0]; pf.u[1] = F[1]; pf.u[2] = F[2]; pf.u[3] = F[3];
#pragma unroll
    for (int nf = 0; nf < 2; ++nf) {
      const int dim = l15 + nf * 16;
      const half8v vf = *(const half8v*)(Vt + dim * VTS + slab0 * 16 +
                                         ks * 32 + lg * 8);
      o[nf] = __builtin_amdgcn_mfma_f32_16x16x32_f16(pf.h, vf, o[nf], 0, 0, 0);
    }
  }

#pragma unroll
  for (int r = 0; r < 4; ++r) {
    const int pxo = lg * 4 + r;
    const int oi = strip_i0 + (pxo >> 3);
    const int oj = j0 + (pxo & 7);
    ushort* op = aout + (size_t)(oi * WW + oj) * CC + head * HD + l15;
    op[0]  = f2h(o[0][r]);
    op[16] = f2h(o[1][r]);
  }
}

// ---- fused: gemm1 | grid barrier | natten | barrier | gemm2 -----------------
__global__ __launch_bounds__(256, 3) void meganat(
    const float* x, const float* qkv_w, const float* qkv_b,
    const float* proj_w, const float* proj_b, const float* rpb,
    float* out, ushort* qkvh, ushort* aouth) {
  __shared__ __align__(16) char smem[33472];
  const int blk = blockIdx.x;
  const int t = threadIdx.x;

  // phase 1: QKV projection, 1536 tiles of 32x64, 2 per block
  gemm_tile<768, 32, 64, false, true>(smem, x, qkv_w, qkv_b, qkvh,
                                      (blk & 127) * 32, (blk >> 7) * 64, t);
  __syncthreads();
  {
    const int t1 = blk + 768;
    gemm_tile<768, 32, 64, false, true>(smem, x, qkv_w, qkv_b, qkvh,
                                        (t1 & 127) * 32, (t1 >> 7) * 64, t);
  }
  grid_barrier(&g_bar1, t);

  // phase 2: neighborhood attention, 512 units (64 tiles x 8 heads)
  if (blk < 512) natten_unit(smem, qkvh, rpb, aouth, blk & 63, blk >> 6, t);
  grid_barrier(&g_bar2, t);

  // counter reset for next launch (graph replay): ack + block0 resets
  if (t == 0) {
    __hip_atomic_fetch_add(&g_ack, 1u, __ATOMIC_RELAXED,
                           __HIP_MEMORY_SCOPE_AGENT);
    if (blk == 0) {
      while (__hip_atomic_load(&g_ack, __ATOMIC_RELAXED,
                               __HIP_MEMORY_SCOPE_AGENT) < NBLK)
        __builtin_amdgcn_s_sleep(8);
      __hip_atomic_store(&g_bar1, 0u, __ATOMIC_RELAXED,
                         __HIP_MEMORY_SCOPE_AGENT);
      __hip_atomic_store(&g_bar2, 0u, __ATOMIC_RELAXED,
                         __HIP_MEMORY_SCOPE_AGENT);
      __hip_atomic_store(&g_ack, 0u, __ATOMIC_RELAXED,
                         __HIP_MEMORY_SCOPE_AGENT);
    }
  }

  // phase 3: output projection, 1024 tiles of 32x32
  gemm_tile<256, 32, 32, true, false>(smem, aouth, proj_w, proj_b, out,
                                      (blk & 127) * 32, (blk >> 7) * 32, t);
  if (blk < 256) {
    __syncthreads();
    const int t1 = blk + 768;
    gemm_tile<256, 32, 32, true, false>(smem, aouth, proj_w, proj_b, out,
                                        (t1 & 127) * 32, (t1 >> 7) * 32, t);
  }
}

extern "C" void kernel_launch(void* const* d_in, const int* in_sizes, int n_in,
                              void* d_out, int out_size, void* d_ws, size_t ws_size,
                              hipStream_t stream) {
  const float* x      = (const float*)d_in[0];
  const float* qkv_w  = (const float*)d_in[1];
  const float* qkv_b  = (const float*)d_in[2];
  const float* proj_w = (const float*)d_in[3];
  const float* proj_b = (const float*)d_in[4];
  const float* rpb    = (const float*)d_in[5];
  float* out = (float*)d_out;

  ushort* qkvh  = (ushort*)d_ws;            // [4096,768] f16
  ushort* aouth = qkvh + 3145728;           // [4096,256] f16

  meganat<<<dim3(NBLK), dim3(256), 0, stream>>>(
      x, qkv_w, qkv_b, proj_w, proj_b, rpb, out, qkvh, aouth);
}

// Round 18
// 54.732 us; speedup vs baseline: 3.8778x; 3.7792x over previous
//
#include <hip/hip_runtime.h>
#include <math.h>

#define HH 64
#define WW 64
#define CC 256
#define NHEAD 8
#define HD 32
#define KW 7

#define KR 40    // natten K LDS row stride (u16)
#define VTS 232  // natten Vt row stride (u16)

typedef _Float16 half8v __attribute__((ext_vector_type(8)));
typedef __fp16 fp16x2 __attribute__((ext_vector_type(2)));
typedef float float4v __attribute__((ext_vector_type(4)));

// Monotonic half-tile counters (zero-init at load; never reset -> graph-replay
// safe via mod-8 winner test). 64B padding: each counter on its own cacheline.
struct PadCnt { unsigned v; unsigned pad[15]; };
__device__ PadCnt half_cnt[128];

__device__ __forceinline__ unsigned pkrtz(float lo, float hi) {
  union { fp16x2 h; unsigned u; } c;
  c.h = __builtin_amdgcn_cvt_pkrtz(lo, hi);
  return c.u;
}
__device__ __forceinline__ ushort f2h(float f) {
  union { _Float16 h; ushort u; } c;
  c.h = (_Float16)f;
  return c.u;
}

// ---- standalone f16 MFMA GEMM for QKV projection (R12's gemm5h, proven) -----
template <int N, int BM, int BN, bool ABF, bool OB>
__global__ __launch_bounds__(256) void gemm5h(
    const void* __restrict__ Ap, const float* __restrict__ Bw,
    const float* __restrict__ bias, void* __restrict__ Cd) {
  constexpr int SEGA = BM / 32;
  constexpr int SEGB = BN / 32;
  constexpr int MF = BM / 32;
  constexpr int NF = BN / 32;

  __shared__ ushort As[2][BM * 64];
  __shared__ ushort Bs[2][BN * 64];

  const int t = threadIdx.x;
  const int lane = t & 63;
  const int wave = t >> 6;
  const int bm = blockIdx.x * BM;
  const int bn = blockIdx.y * BN;

  const float*  Aw = (const float*)Ap;
  const ushort* Ab = (const ushort*)Ap;

  float fA[2][SEGA][8];
  float fB[2][SEGB][8];
  uint4 wA[2][SEGA];

#define LOADA(c, s)                                                            \
  {                                                                            \
    _Pragma("unroll") for (int sa = 0; sa < SEGA; ++sa) {                      \
      const int seg = sa * 256 + t;                                            \
      const int row = seg >> 3;                                                \
      const int q8 = seg & 7;                                                  \
      if (ABF) {                                                               \
        wA[s][sa] =                                                            \
            *(const uint4*)(Ab + (size_t)(bm + row) * 256 + (c) * 64 + q8 * 8);\
      } else {                                                                 \
        const float* p_ = Aw + (size_t)(bm + row) * 256 + (c) * 64 + q8 * 8;   \
        *(float4*)&fA[s][sa][0] = *(const float4*)(p_);                        \
        *(float4*)&fA[s][sa][4] = *(const float4*)(p_ + 4);                    \
      }                                                                        \
    }                                                                          \
  }

#define LOADB(c, s)                                                            \
  {                                                                            \
    _Pragma("unroll") for (int sb = 0; sb < SEGB; ++sb) {                      \
      const int seg = sb * 256 + t;                                            \
      const int row = seg >> 3;                                                \
      const int q8 = seg & 7;                                                  \
      const float* p_ = Bw + (size_t)(bn + row) * 256 + (c) * 64 + q8 * 8;     \
      *(float4*)&fB[s][sb][0] = *(const float4*)(p_);                          \
      *(float4*)&fB[s][sb][4] = *(const float4*)(p_ + 4);                      \
    }                                                                          \
  }

#define WRITEC(b, s)                                                           \
  {                                                                            \
    _Pragma("unroll") for (int sa = 0; sa < SEGA; ++sa) {                      \
      const int seg = sa * 256 + t;                                            \
      const int row = seg >> 3;                                                \
      const int q8 = seg & 7;                                                  \
      const int lin = row * 128 + q8 * 16;                                     \
      const int sw = (row & 7) << 4;                                           \
      uint4 w_;                                                                \
      if (ABF) {                                                               \
        w_ = wA[s][sa];                                                        \
      } else {                                                                 \
        w_.x = pkrtz(fA[s][sa][0], fA[s][sa][1]);                              \
        w_.y = pkrtz(fA[s][sa][2], fA[s][sa][3]);                              \
        w_.z = pkrtz(fA[s][sa][4], fA[s][sa][5]);                              \
        w_.w = pkrtz(fA[s][sa][6], fA[s][sa][7]);                              \
      }                                                                        \
      *(uint4*)((char*)As[b] + (lin ^ sw)) = w_;                               \
    }                                                                          \
    _Pragma("unroll") for (int sb = 0; sb < SEGB; ++sb) {                      \
      const int seg = sb * 256 + t;                                            \
      const int row = seg >> 3;                                                \
      const int q8 = seg & 7;                                                  \
      const int lin = row * 128 + q8 * 16;                                     \
      const int sw = (row & 7) << 4;                                           \
      uint4 w_;                                                                \
      w_.x = pkrtz(fB[s][sb][0], fB[s][sb][1]);                                \
      w_.y = pkrtz(fB[s][sb][2], fB[s][sb][3]);                                \
      w_.z = pkrtz(fB[s][sb][4], fB[s][sb][5]);                                \
      w_.w = pkrtz(fB[s][sb][6], fB[s][sb][7]);                                \
      *(uint4*)((char*)Bs[b] + (lin ^ sw)) = w_;                               \
    }                                                                          \
  }

  const int wr = (wave >> 1) * (BM / 2);
  const int wc = (wave & 1) * (BN / 2);
  const int lrow = lane & 15;
  const int lkb = (lane >> 4) * 16;

  float4v acc[MF][NF];
#pragma unroll
  for (int mf = 0; mf < MF; ++mf)
#pragma unroll
    for (int nf = 0; nf < NF; ++nf) acc[mf][nf] = (float4v){0.f, 0.f, 0.f, 0.f};

  LOADA(0, 0); LOADB(0, 0);
  WRITEC(0, 0);
  LOADA(1, 1); LOADB(1, 1);
  __syncthreads();

#pragma unroll
  for (int c = 0; c < 4; ++c) {
    if (c < 3) WRITEC((c + 1) & 1, (c + 1) & 1);
    if (c < 2) { LOADA(c + 2, c & 1); LOADB(c + 2, c & 1); }
    const char* Al = (const char*)As[c & 1];
    const char* Bl = (const char*)Bs[c & 1];
#pragma unroll
    for (int ks = 0; ks < 2; ++ks) {
      half8v af[MF], bfr[NF];
#pragma unroll
      for (int mf = 0; mf < MF; ++mf) {
        const int row = wr + mf * 16 + lrow;
        const int ad = row * 128 + ks * 64 + lkb;
        af[mf] = *(const half8v*)(Al + (ad ^ ((row & 7) << 4)));
      }
#pragma unroll
      for (int nf = 0; nf < NF; ++nf) {
        const int row = wc + nf * 16 + lrow;
        const int bd = row * 128 + ks * 64 + lkb;
        bfr[nf] = *(const half8v*)(Bl + (bd ^ ((row & 7) << 4)));
      }
#pragma unroll
      for (int mf = 0; mf < MF; ++mf)
#pragma unroll
        for (int nf = 0; nf < NF; ++nf)
          acc[mf][nf] = __builtin_amdgcn_mfma_f32_16x16x32_f16(
              af[mf], bfr[nf], acc[mf][nf], 0, 0, 0);
    }
    if (c < 3) __syncthreads();
  }
#undef LOADA
#undef LOADB
#undef WRITEC

#pragma unroll
  for (int mf = 0; mf < MF; ++mf) {
#pragma unroll
    for (int nf = 0; nf < NF; ++nf) {
      const int n = bn + wc + nf * 16 + lrow;
      const float bv = bias[n];
      const int m0 = bm + wr + mf * 16 + (lane >> 4) * 4;
      if (OB) {
        ushort* C = (ushort*)Cd;
#pragma unroll
        for (int rr = 0; rr < 4; ++rr)
          C[(size_t)(m0 + rr) * N + n] = f2h(acc[mf][nf][rr] + bv);
      } else {
        float* C = (float*)Cd;
#pragma unroll
        for (int rr = 0; rr < 4; ++rr)
          C[(size_t)(m0 + rr) * N + n] = acc[mf][nf][rr] + bv;
      }
    }
  }
}

// ---- gemm2 half-tile (32 pixels x 64 out-cols), A rows mapped to pixels -----
// A = aouth f16 [4096][256]; rows r -> pixel (pr0 + (r>>3))*64 + j0 + (r&7).
__device__ __forceinline__ void gemm2_half(
    char* smem, const ushort* __restrict__ A, const float* __restrict__ Bw,
    const float* __restrict__ bias, float* __restrict__ Cd,
    int pr0, int j0, int bn, int t) {
  constexpr int ABUF = 32 * 128;  // 4096 B per buffer
  constexpr int BBUF = 64 * 128;  // 8192 B

  char* As0 = smem;
  char* Bs0 = smem + 2 * ABUF;

  const int lane = t & 63;
  const int wave = t >> 6;

  uint4 wA[2];
  float fB[2][2][8];

#define LOADA2(c, s)                                                           \
  {                                                                            \
    const int row = t >> 3;                                                    \
    const int q8 = t & 7;                                                      \
    const int pix = (pr0 + (row >> 3)) * 64 + j0 + (row & 7);                  \
    wA[s] = *(const uint4*)(A + (size_t)pix * 256 + (c) * 64 + q8 * 8);        \
  }

#define LOADB2(c, s)                                                           \
  {                                                                            \
    _Pragma("unroll") for (int sb = 0; sb < 2; ++sb) {                         \
      const int seg = sb * 256 + t;                                            \
      const int row = seg >> 3;                                                \
      const int q8 = seg & 7;                                                  \
      const float* p_ = Bw + (size_t)(bn + row) * 256 + (c) * 64 + q8 * 8;     \
      *(float4*)&fB[s][sb][0] = *(const float4*)(p_);                          \
      *(float4*)&fB[s][sb][4] = *(const float4*)(p_ + 4);                      \
    }                                                                          \
  }

#define WRITEC2(b, s)                                                          \
  {                                                                            \
    {                                                                          \
      const int row = t >> 3;                                                  \
      const int q8 = t & 7;                                                    \
      const int lin = row * 128 + q8 * 16;                                     \
      const int sw = (row & 7) << 4;                                           \
      *(uint4*)(As0 + (b) * ABUF + (lin ^ sw)) = wA[s];                        \
    }                                                                          \
    _Pragma("unroll") for (int sb = 0; sb < 2; ++sb) {                         \
      const int seg = sb * 256 + t;                                            \
      const int row = seg >> 3;                                                \
      const int q8 = seg & 7;                                                  \
      const int lin = row * 128 + q8 * 16;                                     \
      const int sw = (row & 7) << 4;                                           \
      uint4 w_;                                                                \
      w_.x = pkrtz(fB[s][sb][0], fB[s][sb][1]);                                \
      w_.y = pkrtz(fB[s][sb][2], fB[s][sb][3]);                                \
      w_.z = pkrtz(fB[s][sb][4], fB[s][sb][5]);                                \
      w_.w = pkrtz(fB[s][sb][6], fB[s][sb][7]);                                \
      *(uint4*)(Bs0 + (b) * BBUF + (lin ^ sw)) = w_;                           \
    }                                                                          \
  }

  const int wr = (wave >> 1) * 16;  // BM/2 = 16
  const int wc = (wave & 1) * 32;   // BN/2 = 32
  const int lrow = lane & 15;
  const int lkb = (lane >> 4) * 16;

  float4v acc[2] = {{0.f, 0.f, 0.f, 0.f}, {0.f, 0.f, 0.f, 0.f}};

  LOADA2(0, 0); LOADB2(0, 0);
  WRITEC2(0, 0);
  LOADA2(1, 1); LOADB2(1, 1);
  __syncthreads();

#pragma unroll
  for (int c = 0; c < 4; ++c) {
    if (c < 3) WRITEC2((c + 1) & 1, (c + 1) & 1);
    if (c < 2) { LOADA2(c + 2, c & 1); LOADB2(c + 2, c & 1); }
    const char* Al = As0 + (c & 1) * ABUF;
    const char* Bl = Bs0 + (c & 1) * BBUF;
#pragma unroll
    for (int ks = 0; ks < 2; ++ks) {
      const int arow = wr + lrow;
      const int ad = arow * 128 + ks * 64 + lkb;
      const half8v af = *(const half8v*)(Al + (ad ^ ((arow & 7) << 4)));
      half8v bfr[2];
#pragma unroll
      for (int nf = 0; nf < 2; ++nf) {
        const int row = wc + nf * 16 + lrow;
        const int bd = row * 128 + ks * 64 + lkb;
        bfr[nf] = *(const half8v*)(Bl + (bd ^ ((row & 7) << 4)));
      }
#pragma unroll
      for (int nf = 0; nf < 2; ++nf)
        acc[nf] = __builtin_amdgcn_mfma_f32_16x16x32_f16(af, bfr[nf], acc[nf],
                                                         0, 0, 0);
    }
    if (c < 3) __syncthreads();
  }
#undef LOADA2
#undef LOADB2
#undef WRITEC2

#pragma unroll
  for (int nf = 0; nf < 2; ++nf) {
    const int n = bn + wc + nf * 16 + lrow;
    const float bv = bias[n];
    const int m0 = wr + (lane >> 4) * 4;
#pragma unroll
    for (int rr = 0; rr < 4; ++rr) {
      const int mrow = m0 + rr;
      const int pix = (pr0 + (mrow >> 3)) * 64 + j0 + (mrow & 7);
      Cd[(size_t)pix * 256 + n] = acc[nf][rr] + bv;
    }
  }
}

// ---- fused natten + winner-gemm2 kernel -------------------------------------
__global__ __launch_bounds__(256) void natg2(
    const ushort* __restrict__ qkv, const float* __restrict__ rpb,
    const float* __restrict__ proj_w, const float* __restrict__ proj_b,
    ushort* __restrict__ aout, float* __restrict__ out) {
  __shared__ __align__(16) char smem[33472];
  __shared__ int winflag[2];

  ushort* Ks = (ushort*)smem;
  ushort* Vt = (ushort*)(smem + 17920);
  float*  Rs = (float*)(smem + 32768);

  const int tile = blockIdx.x;
  const int head = blockIdx.y;
  const int t = threadIdx.x;
  const int i0 = (tile >> 3) * 8, j0 = (tile & 7) * 8;
  const int hs = min(max(i0 - 3, 0), HH - 14);
  const int ws = min(max(j0 - 3, 0), WW - 14);
  const int l = t & 63;
  const int wv = t >> 6;

  // ---------------- natten unit (R13 body, proven) ----------------
  if (t < 169) Rs[t] = rpb[head * 169 + t];

  if (t < 112) {
    const int ent2 = t >> 2;
    const int hr = ent2 >> 1, hc = 14 + (ent2 & 1);
    const uint4 z = {0u, 0u, 0u, 0u};
    *(uint4*)(Ks + (hr * 16 + hc) * KR + (t & 3) * 8) = z;
  }
#pragma unroll
  for (int it = 0; it < 2; ++it) {
    const int task = it * 256 + t;
    const int d = task >> 4, hr = task & 15;
    if (hr < 14) *(unsigned*)(Vt + d * VTS + hr * 16 + 14) = 0u;
  }

#pragma unroll
  for (int s = 0; s < 4; ++s) {
    if (t < 196) {
      const int hr = (t * 2341) >> 15;
      const int hc = t - hr * 14;
      const int g = (hs + hr) * WW + (ws + hc);
      const int col = hr * 16 + hc;
      const uint4 kv = *(const uint4*)(qkv + (size_t)g * 768 + 256 + head * HD + s * 8);
      *(uint4*)(Ks + col * KR + s * 8) = kv;
      const uint4 vv = *(const uint4*)(qkv + (size_t)g * 768 + 512 + head * HD + s * 8);
      const int d0 = s * 8;
      Vt[(d0 + 0) * VTS + col] = (ushort)(vv.x);
      Vt[(d0 + 1) * VTS + col] = (ushort)(vv.x >> 16);
      Vt[(d0 + 2) * VTS + col] = (ushort)(vv.y);
      Vt[(d0 + 3) * VTS + col] = (ushort)(vv.y >> 16);
      Vt[(d0 + 4) * VTS + col] = (ushort)(vv.z);
      Vt[(d0 + 5) * VTS + col] = (ushort)(vv.z >> 16);
      Vt[(d0 + 6) * VTS + col] = (ushort)(vv.w);
      Vt[(d0 + 7) * VTS + col] = (ushort)(vv.w >> 16);
    }
  }
  __syncthreads();

  const int strip_i0 = i0 + wv * 2;
  const int lg = l >> 4;
  const int l15 = l & 15;

  const int pi = strip_i0 + (l15 >> 3);
  const int pj = j0 + (l15 & 7);
  const int si = min(max(pi - 3, 0), HH - KW);
  const int sj = min(max(pj - 3, 0), WW - KW);
  const int si_min = min(max(strip_i0 - 3, 0), HH - KW);
  const int slab0 = min(si_min - hs, 6);

  const half8v qf = *(const half8v*)(qkv + (size_t)(pi * WW + pj) * 768 +
                                     head * HD + lg * 8);

  float4v s8[8];
  const float4v zz = {0.f, 0.f, 0.f, 0.f};
#pragma unroll
  for (int g = 0; g < 8; ++g) {
    const int ent = (slab0 + g) * 16 + l15;
    const half8v kf = *(const half8v*)(Ks + ent * KR + lg * 8);
    s8[g] = __builtin_amdgcn_mfma_f32_16x16x32_f16(kf, qf, zz, 0, 0, 0);
  }

  const int lr0 = si - hs;
  const int lc0 = sj - ws;
  const int abase = slab0 - lr0;
  const int rowb = ((si - pi + 6) + abase) * 13 + (sj - pj + 6) - lc0;
  const float scale = 0.17677669529663687f;

  float e8[8][4];
  float ssum = 0.f;
#pragma unroll
  for (int g = 0; g < 8; ++g) {
    const int a = abase + g;
    const bool va = (unsigned)a < 7u;
    const int idxg = min(max(rowb + g * 13, 0), 153);
#pragma unroll
    for (int r = 0; r < 4; ++r) {
      const int hc = lg * 4 + r;
      const bool vc = (unsigned)(hc - lc0) < 7u;
      const float ev = __expf(fmaf(s8[g][r], scale, Rs[idxg + hc]));
      const float em = (va && vc) ? ev : 0.f;
      e8[g][r] = em;
      ssum += em;
    }
  }
  ssum += __shfl_xor(ssum, 16);
  ssum += __shfl_xor(ssum, 32);
  const float inv = 1.f / ssum;

  unsigned Wp[8][2];
#pragma unroll
  for (int g = 0; g < 8; ++g) {
    Wp[g][0] = pkrtz(e8[g][0] * inv, e8[g][1] * inv);
    Wp[g][1] = pkrtz(e8[g][2] * inv, e8[g][3] * inv);
  }

  float4v o[2] = {zz, zz};
#pragma unroll
  for (int ks = 0; ks < 4; ++ks) {
    unsigned F[4];
#pragma unroll
    for (int f = 0; f < 4; ++f) {
      const int src = l15 + (((lg & 1) * 2 + (f >> 1)) << 4);
      const unsigned va = __shfl(Wp[2 * ks][f & 1], src);
      const unsigned vb = __shfl(Wp[2 * ks + 1][f & 1], src);
      F[f] = (lg >> 1) ? vb : va;
    }
    union { unsigned u[4]; half8v h; } pf;
    pf.u[0] = F[0]; pf.u[1] = F[1]; pf.u[2] = F[2]; pf.u[3] = F[3];
#pragma unroll
    for (int nf = 0; nf < 2; ++nf) {
      const int dim = l15 + nf * 16;
      const half8v vf = *(const half8v*)(Vt + dim * VTS + slab0 * 16 +
                                         ks * 32 + lg * 8);
      o[nf] = __builtin_amdgcn_mfma_f32_16x16x32_f16(pf.h, vf, o[nf], 0, 0, 0);
    }
  }

#pragma unroll
  for (int r = 0; r < 4; ++r) {
    const int pxo = lg * 4 + r;
    const int oi = strip_i0 + (pxo >> 3);
    const int oj = j0 + (pxo & 7);
    ushort* op = aout + (size_t)(oi * WW + oj) * CC + head * HD + l15;
    op[0]  = f2h(o[0][r]);
    op[16] = f2h(o[1][r]);
  }

  // ---------------- winner protocol: last head-block per half-tile -----------
  __syncthreads();
  if (t == 0) {
    __threadfence();  // release this block's aout writes
    const unsigned o0 = __hip_atomic_fetch_add(
        &half_cnt[tile * 2 + 0].v, 1u, __ATOMIC_RELAXED,
        __HIP_MEMORY_SCOPE_AGENT);
    const unsigned o1 = __hip_atomic_fetch_add(
        &half_cnt[tile * 2 + 1].v, 1u, __ATOMIC_RELAXED,
        __HIP_MEMORY_SCOPE_AGENT);
    winflag[0] = ((o0 & 7u) == 7u);
    winflag[1] = ((o1 & 7u) == 7u);
    if (winflag[0] | winflag[1]) __threadfence();  // acquire others' aout
  }
  __syncthreads();

#pragma unroll
  for (int h = 0; h < 2; ++h) {
    if (winflag[h]) {
      const int pr0 = i0 + 4 * h;
#pragma unroll
      for (int bn = 0; bn < 256; bn += 64) {
        __syncthreads();  // protect LDS reuse between chunks
        gemm2_half(smem, aout, proj_w, proj_b, out, pr0, j0, bn, t);
      }
    }
  }
}

extern "C" void kernel_launch(void* const* d_in, const int* in_sizes, int n_in,
                              void* d_out, int out_size, void* d_ws, size_t ws_size,
                              hipStream_t stream) {
  const float* x      = (const float*)d_in[0];
  const float* qkv_w  = (const float*)d_in[1];
  const float* qkv_b  = (const float*)d_in[2];
  const float* proj_w = (const float*)d_in[3];
  const float* proj_b = (const float*)d_in[4];
  const float* rpb    = (const float*)d_in[5];
  float* out = (float*)d_out;

  ushort* qkvh  = (ushort*)d_ws;            // [4096,768] f16
  ushort* aouth = qkvh + 3145728;           // [4096,256] f16

  // 1) QKV projection: 32x64 tiles, 1536 blocks (6/CU)
  gemm5h<768, 32, 64, false, true><<<dim3(128, 12), 256, 0, stream>>>(
      x, qkv_w, qkv_b, qkvh);

  // 2) fused neighborhood attention + winner-computed output projection
  natg2<<<dim3(64, NHEAD), 256, 0, stream>>>(
      qkvh, rpb, proj_w, proj_b, aouth, out);
}

// Round 20
// 34.954 us; speedup vs baseline: 6.0719x; 1.5658x over previous
//
#include <hip/hip_runtime.h>
#include <math.h>

#define HH 64
#define WW 64
#define CC 256
#define NHEAD 8
#define HD 32
#define KW 7

#define KR 40     // K LDS row stride (u16)
#define VTS2 152  // Vt row stride (u16)
#define SLOTB 21248   // bytes per head slot: K 144*40*2=11520 + Vt 32*152*2=9728
#define AOUTB 84992   // aoutL offset (4 slots)
#define RSB 93440     // Rs offset (aoutL 16*264*2 = 8448)
#define SMEMB 98848   // total (Rs 1352*4 = 5408)

typedef _Float16 half8v __attribute__((ext_vector_type(8)));
typedef __fp16 fp16x2 __attribute__((ext_vector_type(2)));
typedef float float4v __attribute__((ext_vector_type(4)));

__device__ __forceinline__ unsigned pkrtz(float lo, float hi) {
  union { fp16x2 h; unsigned u; } c;
  c.h = __builtin_amdgcn_cvt_pkrtz(lo, hi);
  return c.u;
}
__device__ __forceinline__ ushort f2h(float f) {
  union { _Float16 h; ushort u; } c;
  c.h = (_Float16)f;
  return c.u;
}

// ---- f16 MFMA GEMM for QKV projection (R12's gemm5h, proven) ----------------
template <int N, int BM, int BN, bool ABF, bool OB>
__global__ __launch_bounds__(256) void gemm5h(
    const void* __restrict__ Ap, const float* __restrict__ Bw,
    const float* __restrict__ bias, void* __restrict__ Cd) {
  constexpr int SEGA = BM / 32;
  constexpr int SEGB = BN / 32;
  constexpr int MF = BM / 32;
  constexpr int NF = BN / 32;

  __shared__ ushort As[2][BM * 64];
  __shared__ ushort Bs[2][BN * 64];

  const int t = threadIdx.x;
  const int lane = t & 63;
  const int wave = t >> 6;
  const int bm = blockIdx.x * BM;
  const int bn = blockIdx.y * BN;

  const float*  Aw = (const float*)Ap;
  const ushort* Ab = (const ushort*)Ap;

  float fA[2][SEGA][8];
  float fB[2][SEGB][8];
  uint4 wA[2][SEGA];

#define LOADA(c, s)                                                            \
  {                                                                            \
    _Pragma("unroll") for (int sa = 0; sa < SEGA; ++sa) {                      \
      const int seg = sa * 256 + t;                                            \
      const int row = seg >> 3;                                                \
      const int q8 = seg & 7;                                                  \
      if (ABF) {                                                               \
        wA[s][sa] =                                                            \
            *(const uint4*)(Ab + (size_t)(bm + row) * 256 + (c) * 64 + q8 * 8);\
      } else {                                                                 \
        const float* p_ = Aw + (size_t)(bm + row) * 256 + (c) * 64 + q8 * 8;   \
        *(float4*)&fA[s][sa][0] = *(const float4*)(p_);                        \
        *(float4*)&fA[s][sa][4] = *(const float4*)(p_ + 4);                    \
      }                                                                        \
    }                                                                          \
  }

#define LOADB(c, s)                                                            \
  {                                                                            \
    _Pragma("unroll") for (int sb = 0; sb < SEGB; ++sb) {                      \
      const int seg = sb * 256 + t;                                            \
      const int row = seg >> 3;                                                \
      const int q8 = seg & 7;                                                  \
      const float* p_ = Bw + (size_t)(bn + row) * 256 + (c) * 64 + q8 * 8;     \
      *(float4*)&fB[s][sb][0] = *(const float4*)(p_);                          \
      *(float4*)&fB[s][sb][4] = *(const float4*)(p_ + 4);                      \
    }                                                                          \
  }

#define WRITEC(b, s)                                                           \
  {                                                                            \
    _Pragma("unroll") for (int sa = 0; sa < SEGA; ++sa) {                      \
      const int seg = sa * 256 + t;                                            \
      const int row = seg >> 3;                                                \
      const int q8 = seg & 7;                                                  \
      const int lin = row * 128 + q8 * 16;                                     \
      const int sw = (row & 7) << 4;                                           \
      uint4 w_;                                                                \
      if (ABF) {                                                               \
        w_ = wA[s][sa];                                                        \
      } else {                                                                 \
        w_.x = pkrtz(fA[s][sa][0], fA[s][sa][1]);                              \
        w_.y = pkrtz(fA[s][sa][2], fA[s][sa][3]);                              \
        w_.z = pkrtz(fA[s][sa][4], fA[s][sa][5]);                              \
        w_.w = pkrtz(fA[s][sa][6], fA[s][sa][7]);                              \
      }                                                                        \
      *(uint4*)((char*)As[b] + (lin ^ sw)) = w_;                               \
    }                                                                          \
    _Pragma("unroll") for (int sb = 0; sb < SEGB; ++sb) {                      \
      const int seg = sb * 256 + t;                                            \
      const int row = seg >> 3;                                                \
      const int q8 = seg & 7;                                                  \
      const int lin = row * 128 + q8 * 16;                                     \
      const int sw = (row & 7) << 4;                                           \
      uint4 w_;                                                                \
      w_.x = pkrtz(fB[s][sb][0], fB[s][sb][1]);                                \
      w_.y = pkrtz(fB[s][sb][2], fB[s][sb][3]);                                \
      w_.z = pkrtz(fB[s][sb][4], fB[s][sb][5]);                                \
      w_.w = pkrtz(fB[s][sb][6], fB[s][sb][7]);                                \
      *(uint4*)((char*)Bs[b] + (lin ^ sw)) = w_;                               \
    }                                                                          \
  }

  const int wr = (wave >> 1) * (BM / 2);
  const int wc = (wave & 1) * (BN / 2);
  const int lrow = lane & 15;
  const int lkb = (lane >> 4) * 16;

  float4v acc[MF][NF];
#pragma unroll
  for (int mf = 0; mf < MF; ++mf)
#pragma unroll
    for (int nf = 0; nf < NF; ++nf) acc[mf][nf] = (float4v){0.f, 0.f, 0.f, 0.f};

  LOADA(0, 0); LOADB(0, 0);
  WRITEC(0, 0);
  LOADA(1, 1); LOADB(1, 1);
  __syncthreads();

#pragma unroll
  for (int c = 0; c < 4; ++c) {
    if (c < 3) WRITEC((c + 1) & 1, (c + 1) & 1);
    if (c < 2) { LOADA(c + 2, c & 1); LOADB(c + 2, c & 1); }
    const char* Al = (const char*)As[c & 1];
    const char* Bl = (const char*)Bs[c & 1];
#pragma unroll
    for (int ks = 0; ks < 2; ++ks) {
      half8v af[MF], bfr[NF];
#pragma unroll
      for (int mf = 0; mf < MF; ++mf) {
        const int row = wr + mf * 16 + lrow;
        const int ad = row * 128 + ks * 64 + lkb;
        af[mf] = *(const half8v*)(Al + (ad ^ ((row & 7) << 4)));
      }
#pragma unroll
      for (int nf = 0; nf < NF; ++nf) {
        const int row = wc + nf * 16 + lrow;
        const int bd = row * 128 + ks * 64 + lkb;
        bfr[nf] = *(const half8v*)(Bl + (bd ^ ((row & 7) << 4)));
      }
#pragma unroll
      for (int mf = 0; mf < MF; ++mf)
#pragma unroll
        for (int nf = 0; nf < NF; ++nf)
          acc[mf][nf] = __builtin_amdgcn_mfma_f32_16x16x32_f16(
              af[mf], bfr[nf], acc[mf][nf], 0, 0, 0);
    }
    if (c < 3) __syncthreads();
  }
#undef LOADA
#undef LOADB
#undef WRITEC

#pragma unroll
  for (int mf = 0; mf < MF; ++mf) {
#pragma unroll
    for (int nf = 0; nf < NF; ++nf) {
      const int n = bn + wc + nf * 16 + lrow;
      const float bv = bias[n];
      const int m0 = bm + wr + mf * 16 + (lane >> 4) * 4;
      if (OB) {
        ushort* C = (ushort*)Cd;
#pragma unroll
        for (int rr = 0; rr < 4; ++rr)
          C[(size_t)(m0 + rr) * N + n] = f2h(acc[mf][nf][rr] + bv);
      } else {
        float* C = (float*)Cd;
#pragma unroll
        for (int rr = 0; rr < 4; ++rr)
          C[(size_t)(m0 + rr) * N + n] = acc[mf][nf][rr] + bv;
      }
    }
  }
}

// ---- natg2c: block-local natten(8 heads) + gemm2 for a 2x8 pixel tile -------
__global__ __launch_bounds__(256) void natg2c(
    const ushort* __restrict__ qkv, const float* __restrict__ rpb,
    const float* __restrict__ proj_w, const float* __restrict__ proj_b,
    float* __restrict__ out) {
  __shared__ __align__(16) char smem[SMEMB];
  float* Rs = (float*)(smem + RSB);
  ushort* aoutL = (ushort*)(smem + AOUTB);

  const int ti = blockIdx.x;
  const int i0 = (ti >> 3) * 2, j0 = (ti & 7) * 8;
  const int hs = min(max(i0 - 3, 0), HH - 8);
  const int ws = min(max(j0 - 3, 0), WW - 14);
  const int t = threadIdx.x;
  const int l = t & 63;
  const int wv = t >> 6;
  const int lg = l >> 4;
  const int l15 = l & 15;

  // stage all heads' rpb
#pragma unroll
  for (int it = 0; it < 6; ++it) {
    const int idx = it * 256 + t;
    if (idx < NHEAD * 169) Rs[idx] = rpb[idx];
  }

  // per-lane geometry (head-independent); slab0 in {0,1}
  const int pi = i0 + (l15 >> 3);
  const int pj = j0 + (l15 & 7);
  const int si = min(max(pi - 3, 0), HH - KW);
  const int sj = min(max(pj - 3, 0), WW - KW);
  const int si_min = min(max(i0 - 3, 0), HH - KW);
  const int slab0 = si_min - hs;
  const int lr0 = si - hs;
  const int lc0 = sj - ws;
  const int abase = slab0 - lr0;
  const int rowb = ((si - pi + 6) + abase) * 13 + (sj - pj + 6) - lc0;
  const float scale = 0.17677669529663687f;
  const float4v zz = {0.f, 0.f, 0.f, 0.f};

#pragma unroll
  for (int pass = 0; pass < 2; ++pass) {
    if (pass == 0) {
      // zero Vt pads (cols 14,15 rows 0..8 + row 8) for all 4 slots
      if (t < 128) {
        const int slot = t >> 5, d = t & 31;
        ushort* vt = (ushort*)(smem + slot * SLOTB + 11520) + d * VTS2;
#pragma unroll
        for (int hr = 0; hr < 9; ++hr) *(unsigned*)(vt + hr * 16 + 14) = 0u;
#pragma unroll
        for (int c = 0; c < 8; ++c) *(unsigned*)(vt + 128 + c * 2) = 0u;
      }
      // zero K halo row 8 (entries 128..143) for all 4 slots: 256 uint4 tasks
      {
        const int slot = t >> 6;
        const int ent = 128 + ((t >> 2) & 15);
        const int seg = t & 3;
        const uint4 z = {0u, 0u, 0u, 0u};
        *(uint4*)((ushort*)(smem + slot * SLOTB) + ent * KR + seg * 8) = z;
      }
    }

    // stage 4 heads' K (row-major) + V (transposed): 896 row-tasks
#pragma unroll
    for (int it = 0; it < 4; ++it) {
      const int task = it * 256 + t;
      if (task < 896) {
        const int hsl = task / 224;
        const int rem = task - hsl * 224;
        const int mat = rem >= 112;
        const int row = rem - mat * 112;
        const int hr = (row * 2341) >> 15;  // row / 14
        const int hc = row - hr * 14;
        const int g = (hs + hr) * WW + (ws + hc);
        const int head = pass * 4 + hsl;
        const int col = hr * 16 + hc;
        const ushort* src = qkv + (size_t)g * 768 + 256 + mat * 256 + head * HD;
        if (!mat) {
          ushort* kd = (ushort*)(smem + hsl * SLOTB) + col * KR;
          *(uint4*)(kd + 0)  = *(const uint4*)(src + 0);
          *(uint4*)(kd + 8)  = *(const uint4*)(src + 8);
          *(uint4*)(kd + 16) = *(const uint4*)(src + 16);
          *(uint4*)(kd + 24) = *(const uint4*)(src + 24);
        } else {
          ushort* vt = (ushort*)(smem + hsl * SLOTB + 11520);
#pragma unroll
          for (int s2 = 0; s2 < 4; ++s2) {
            const uint4 vv = *(const uint4*)(src + s2 * 8);
            const int d0 = s2 * 8;
            vt[(d0 + 0) * VTS2 + col] = (ushort)(vv.x);
            vt[(d0 + 1) * VTS2 + col] = (ushort)(vv.x >> 16);
            vt[(d0 + 2) * VTS2 + col] = (ushort)(vv.y);
            vt[(d0 + 3) * VTS2 + col] = (ushort)(vv.y >> 16);
            vt[(d0 + 4) * VTS2 + col] = (ushort)(vv.z);
            vt[(d0 + 5) * VTS2 + col] = (ushort)(vv.z >> 16);
            vt[(d0 + 6) * VTS2 + col] = (ushort)(vv.w);
            vt[(d0 + 7) * VTS2 + col] = (ushort)(vv.w >> 16);
          }
        }
      }
    }
    __syncthreads();

    // ---- per-wave natten (R13 strip math): head = pass*4 + wv ----
    const int head = pass * 4 + wv;
    const ushort* Ks = (const ushort*)(smem + wv * SLOTB);
    const ushort* Vt = (const ushort*)(smem + wv * SLOTB + 11520);
    const float* Rh = Rs + head * 169;

    const half8v qf = *(const half8v*)(qkv + (size_t)(pi * WW + pj) * 768 +
                                       head * HD + lg * 8);

    float4v s8[8];
#pragma unroll
    for (int g = 0; g < 8; ++g) {
      const int ent = (slab0 + g) * 16 + l15;
      const half8v kf = *(const half8v*)(Ks + ent * KR + lg * 8);
      s8[g] = __builtin_amdgcn_mfma_f32_16x16x32_f16(kf, qf, zz, 0, 0, 0);
    }

    float e8[8][4];
    float ssum = 0.f;
#pragma unroll
    for (int g = 0; g < 8; ++g) {
      const int a = abase + g;
      const bool va = (unsigned)a < 7u;
      const int idxg = min(max(rowb + g * 13, 0), 153);
#pragma unroll
      for (int r = 0; r < 4; ++r) {
        const int hc = lg * 4 + r;
        const bool vc = (unsigned)(hc - lc0) < 7u;
        const float ev = __expf(fmaf(s8[g][r], scale, Rh[idxg + hc]));
        const float em = (va && vc) ? ev : 0.f;
        e8[g][r] = em;
        ssum += em;
      }
    }
    ssum += __shfl_xor(ssum, 16);
    ssum += __shfl_xor(ssum, 32);
    const float inv = 1.f / ssum;

    unsigned Wp[8][2];
#pragma unroll
    for (int g = 0; g < 8; ++g) {
      Wp[g][0] = pkrtz(e8[g][0] * inv, e8[g][1] * inv);
      Wp[g][1] = pkrtz(e8[g][2] * inv, e8[g][3] * inv);
    }

    float4v o[2] = {zz, zz};
#pragma unroll
    for (int ks = 0; ks < 4; ++ks) {
      unsigned F[4];
#pragma unroll
      for (int f = 0; f < 4; ++f) {
        const int src = l15 + (((lg & 1) * 2 + (f >> 1)) << 4);
        const unsigned va = __shfl(Wp[2 * ks][f & 1], src);
        const unsigned vb = __shfl(Wp[2 * ks + 1][f & 1], src);
        F[f] = (lg >> 1) ? vb : va;
      }
      union { unsigned u[4]; half8v h; } pf;
      pf.u[0] = F[0]; pf.u[1] = F[1]; pf.u[2] = F[2]; pf.u[3] = F[3];
#pragma unroll
      for (int nf = 0; nf < 2; ++nf) {
        const int dim = l15 + nf * 16;
        const half8v vf = *(const half8v*)(Vt + dim * VTS2 + slab0 * 16 +
                                           ks * 32 + lg * 8);
        o[nf] = __builtin_amdgcn_mfma_f32_16x16x32_f16(pf.h, vf, o[nf], 0, 0, 0);
      }
    }

#pragma unroll
    for (int r = 0; r < 4; ++r) {
      const int px = lg * 4 + r;
      aoutL[px * 264 + head * HD + l15]      = f2h(o[0][r]);
      aoutL[px * 264 + head * HD + 16 + l15] = f2h(o[1][r]);
    }
    __syncthreads();
  }

  // ---- in-block gemm2: out[16px][256] = aoutL @ proj_w^T + proj_b ----------
  // W chunk staged to LDS (64 rows x 256 halves, stride 264); barrier/chunk.
  ushort* Wc = (ushort*)smem;  // reuse K/V region (64*264*2 = 33792 B)
  const int wrow = t >> 2;         // 0..63
  const int wq = (t & 3) * 64;     // quarter-row base (64 values)

#pragma unroll
  for (int c = 0; c < 4; ++c) {
    __syncthreads();  // protect Wc reuse (prev chunk MFMA done)
    {
      const float* p_ = proj_w + (size_t)(c * 64 + wrow) * 256 + wq;
      ushort* d_ = Wc + wrow * 264 + wq;
#pragma unroll
      for (int s2 = 0; s2 < 4; ++s2) {
        const float4 f0 = *(const float4*)(p_ + s2 * 16);
        const float4 f1 = *(const float4*)(p_ + s2 * 16 + 4);
        const float4 f2 = *(const float4*)(p_ + s2 * 16 + 8);
        const float4 f3 = *(const float4*)(p_ + s2 * 16 + 12);
        uint4 w_;
        w_.x = pkrtz(f0.x, f0.y);
        w_.y = pkrtz(f0.z, f0.w);
        w_.z = pkrtz(f1.x, f1.y);
        w_.w = pkrtz(f1.z, f1.w);
        *(uint4*)(d_ + s2 * 16) = w_;
        w_.x = pkrtz(f2.x, f2.y);
        w_.y = pkrtz(f2.z, f2.w);
        w_.z = pkrtz(f3.x, f3.y);
        w_.w = pkrtz(f3.z, f3.w);
        *(uint4*)(d_ + s2 * 16 + 8) = w_;
      }
    }
    __syncthreads();

    float4v acc = zz;
#pragma unroll
    for (int ks = 0; ks < 8; ++ks) {
      const half8v af = *(const half8v*)(aoutL + l15 * 264 + ks * 32 + lg * 8);
      const half8v bf = *(const half8v*)(Wc + (wv * 16 + l15) * 264 + ks * 32 +
                                         lg * 8);
      acc = __builtin_amdgcn_mfma_f32_16x16x32_f16(af, bf, acc, 0, 0, 0);
    }
    const int n = c * 64 + wv * 16 + l15;
    const float bv = proj_b[n];
#pragma unroll
    for (int r = 0; r < 4; ++r) {
      const int px = lg * 4 + r;
      const int pixel = (i0 + (px >> 3)) * WW + j0 + (px & 7);
      out[(size_t)pixel * CC + n] = acc[r] + bv;
    }
  }
}

extern "C" void kernel_launch(void* const* d_in, const int* in_sizes, int n_in,
                              void* d_out, int out_size, void* d_ws, size_t ws_size,
                              hipStream_t stream) {
  const float* x      = (const float*)d_in[0];
  const float* qkv_w  = (const float*)d_in[1];
  const float* qkv_b  = (const float*)d_in[2];
  const float* proj_w = (const float*)d_in[3];
  const float* proj_b = (const float*)d_in[4];
  const float* rpb    = (const float*)d_in[5];
  float* out = (float*)d_out;

  ushort* qkvh = (ushort*)d_ws;  // [4096,768] f16

  // 1) QKV projection: 32x64 tiles, 1536 blocks (6/CU)
  gemm5h<768, 32, 64, false, true><<<dim3(128, 12), 256, 0, stream>>>(
      x, qkv_w, qkv_b, qkvh);

  // 2) fused block-local natten(8 heads) + output projection per 2x8 tile
  natg2c<<<dim3(256), 256, 0, stream>>>(qkvh, rpb, proj_w, proj_b, out);
}